// Round 4
// baseline (26.223 us; speedup 1.0000x reference)
//
#include <hip/hip_runtime.h>

// HilbertFlatten: out[s] = x[hilbert_decode(s)] for (256,256,256) f32.
// Wave-cooperative: 512 consecutive aligned curve points = one aligned 8^3
// spatial cube (2 KB). Each wave loads its region once via 2x global_load_lds
// (compulsory-only traffic), lanes gather their 2x2x2 cube from LDS with
// conflict-spread ds_read_b64, resolve curve order with a cndmask tree.
// Per-wave private LDS slice -> no __syncthreads, only s_waitcnt vmcnt(0).

typedef __attribute__((address_space(1))) const void global_cvoid;
typedef __attribute__((address_space(3))) void lds_void;

__global__ __launch_bounds__(256) void hilbert_lds_kernel(
    const float* __restrict__ x, float* __restrict__ out, unsigned ngroups) {
    __shared__ float lds[4 * 512];   // 2 KB per wave, 4 waves/block

    // XCD-chunked bijective swizzle (gridDim.x divisible by 8).
    unsigned nb = blockIdx.x;
    unsigned cpx = gridDim.x >> 3;
    unsigned b = (nb & 7u) * cpx + (nb >> 3);
    unsigned tid = threadIdx.x;
    unsigned gid = b * 256u + tid;
    if (gid >= ngroups) return;
    unsigned S = gid << 3;           // base curve index of this lane's cube
    unsigned lane = tid & 63u;
    unsigned wave = tid >> 6;

    // ---- decode S -> cube base coords + affine bit-0 byte B[3] ----
    unsigned g = S ^ (S >> 1);
    unsigned G[3];
#pragma unroll
    for (int d = 0; d < 3; ++d) {
        unsigned v = (g >> (2 - d)) & 0x00249249u;
        v = (v ^ (v >> 2)) & 0x030C30C3u;
        v = (v ^ (v >> 4)) & 0x0300F00Fu;
        v = (v ^ (v >> 8)) & 0x000000FFu;
        G[d] = v;
    }
    G[0] |= 0x100u;   // probe channels: bits 8..10 identity, bit 11 constant
    G[1] |= 0x200u;
    G[2] |= 0x400u;
#pragma unroll
    for (int bit = 6; bit >= 0; --bit) {
        const unsigned low = ((1u << (7 - bit)) - 1u) | 0x0F00u;
#pragma unroll
        for (int dim = 2; dim >= 0; --dim) {
            unsigned m = (G[dim] >> (7 - bit)) & 1u;
            unsigned diff = (G[0] ^ G[dim]) & low;
            unsigned t = diff & (m - 1u);
            G[0] ^= ((0u - m) & low) ^ t;
            G[dim] ^= t;
        }
    }
    unsigned s3m = 0u - ((S >> 3) & 1u);
    unsigned V0 = (0xF0u ^ s3m) & 0xFFu;
    const unsigned V1 = 0x3Cu, V2 = 0x66u;
    unsigned B[3];
#pragma unroll
    for (int d = 0; d < 3; ++d) {
        unsigned cd = 0u - ((G[d] >> 11) & 1u);
        unsigned a0 = (0u - ((G[d] >> 8) & 1u)) ^ cd;
        unsigned a1 = (0u - ((G[d] >> 9) & 1u)) ^ cd;
        unsigned a2 = (0u - ((G[d] >> 10) & 1u)) ^ cd;
        B[d] = ((a0 & V0) ^ (a1 & V1) ^ (a2 & V2) ^ cd) & 0xFFu;
    }
    unsigned baseflat = ((G[0] & 0xFEu) << 16) | ((G[1] & 0xFEu) << 8)
                      | (G[2] & 0xFEu);

    // ---- cooperative load: 8^3 region (wave-uniform) into LDS ----
    unsigned regionflat = baseflat & 0x00F8F8F8u;   // same for all 64 lanes
    const float* gbase = x + regionflat;
    unsigned dxl = lane >> 4;            // row R = h*32 + (lane>>1)
    unsigned dyl = (lane >> 1) & 7u;
    unsigned half = lane & 1u;
    auto lds3 = (__attribute__((address_space(3))) float*)lds;
#pragma unroll
    for (unsigned h = 0; h < 2; ++h) {
        const float* src = gbase + (h * 4u + dxl) * 65536u + dyl * 256u + half * 4u;
        __builtin_amdgcn_global_load_lds((global_cvoid*)src,
                                         (lds_void*)(lds3 + wave * 512u + h * 256u),
                                         16, 0, 0);
    }
    asm volatile("s_waitcnt vmcnt(0)" ::: "memory");

    // ---- gather own 2x2x2 cube from LDS (conflict-spread corner order) ----
    unsigned bx = (baseflat >> 16) & 6u;
    unsigned by = (baseflat >> 8) & 6u;
    unsigned bz = baseflat & 6u;
    unsigned bxp = (bx >> 1) & 1u;
    unsigned byp = (by >> 1) & 1u;
    const float* lw = lds + wave * 512u;
    // step k reads corner (i,j) = ((k>>1)^byp, (k&1)^bxp)
    unsigned i0 = byp,      j0 = bxp;
    unsigned i1 = byp,      j1 = bxp ^ 1u;
    unsigned i2 = byp ^ 1u, j2 = bxp;
    unsigned i3 = byp ^ 1u, j3 = bxp ^ 1u;
    float2 r0 = *(const float2*)&lw[(bx + i0) * 64u + (by + j0) * 8u + bz];
    float2 r1 = *(const float2*)&lw[(bx + i1) * 64u + (by + j1) * 8u + bz];
    float2 r2 = *(const float2*)&lw[(bx + i2) * 64u + (by + j2) * 8u + bz];
    float2 r3 = *(const float2*)&lw[(bx + i3) * 64u + (by + j3) * 8u + bz];
    // un-permute: q[i][j] at corner (x+i, y+j)
    bool sx = bxp != 0u, sy = byp != 0u;
    float2 a0 = sx ? r1 : r0;
    float2 a1 = sx ? r0 : r1;
    float2 a2 = sx ? r3 : r2;
    float2 a3 = sx ? r2 : r3;
    float2 q00 = sy ? a2 : a0;
    float2 q01 = sy ? a3 : a1;
    float2 q10 = sy ? a0 : a2;
    float2 q11 = sy ? a1 : a3;

    float out8[8];
#pragma unroll
    for (int rr = 0; rr < 8; ++rr) {
        unsigned f0 = (B[0] >> rr) & 1u;   // x bit
        unsigned f1 = (B[1] >> rr) & 1u;   // y bit
        unsigned f2 = (B[2] >> rr) & 1u;   // z bit
        float2 t0 = f1 ? q01 : q00;
        float2 t1 = f1 ? q11 : q10;
        float2 t  = f0 ? t1 : t0;
        out8[rr] = f2 ? t.y : t.x;
    }
    float4* o4 = (float4*)(out + S);
    o4[0] = make_float4(out8[0], out8[1], out8[2], out8[3]);
    o4[1] = make_float4(out8[4], out8[5], out8[6], out8[7]);
}

extern "C" void kernel_launch(void* const* d_in, const int* in_sizes, int n_in,
                              void* d_out, int out_size, void* d_ws, size_t ws_size,
                              hipStream_t stream) {
    const float* x = (const float*)d_in[0];
    float* out = (float*)d_out;
    unsigned n = (unsigned)out_size;               // 16777216
    unsigned ngroups = n >> 3;                     // 2097152
    unsigned blocks = (ngroups + 255u) / 256u;     // 8192 (divisible by 8)
    hilbert_lds_kernel<<<blocks, 256, 0, stream>>>(x, out, ngroups);
}